// Round 11
// baseline (3880.628 us; speedup 1.0000x reference)
//
#include <hip/hip_runtime.h>
#include <math.h>

// ---------------------------------------------------------------------------
// TransformerDecoder: weight-stationary persistent dataflow decode, v5.
// B=8, S_SRC=256, T=64, D=256, H=8, HD=32, DFF=1024, NC=128, L=2. fp32.
// 248 blocks (1/CU). v5: TAGGED TRANSPORT — every inter-block float travels
// as a (seq<<32 | float_bits) 8-byte word via relaxed agent atomics.
// Consumers poll their own data words (detect==fetch, 1 MALL RT); no flag
// arrays, no producer drain barrier, no wave-0 poll convergence.
//   S1L0 [0,16):  (h,bhalf)   4b, SA layer0
//   S1L1 [16,48): (h,bpair)   2b, SA layer1 (+r3 assembly)
//   S2  [48,176): (b,h,l)     p1-sum, CA (memKV in LDS), proj partial
//   S3 [176,240): (l,cg16,bh) p2-sum, FFN1 + FFN2 partial
//   HEAD[240,248):(b)         r3(l1), op_w1+BN+relu, logits, out, emb->xrow
// Tags: fv=2t+l+1 for layer stages; t(+1) for xrow/r3. memset tag region
// each call (ABA-safe across graph replays; 0xAA poison never matches).
// ---------------------------------------------------------------------------

#define EPS_ 1e-5f
#define SCALE_ 0.17677669529663687f   // 1/sqrt(32)
#define BNS 0.99999500003749969f      // 1/sqrt(1+1e-5)
#define DEV __device__ __forceinline__
#define DYNF 36864                     // LDS floats per block (147456 B)

typedef unsigned long long u64;

#define D4(a,b) ((a).x*(b).x+(a).y*(b).y+(a).z*(b).z+(a).w*(b).w)
#define F4(p)  (*(float4*)(p))
#define CF4(p) (*(const float4*)(p))

DEV u64  ald64(const u64* p){return __hip_atomic_load(p,__ATOMIC_RELAXED,__HIP_MEMORY_SCOPE_AGENT);}
DEV void ast64(u64* p,u64 v){__hip_atomic_store(p,v,__ATOMIC_RELAXED,__HIP_MEMORY_SCOPE_AGENT);}
DEV u64   mkw(float v,int s){return ((u64)(unsigned)s<<32)|(u64)__float_as_uint(v);}
DEV int   tg(u64 w){return (int)(unsigned)(w>>32);}
DEV float vlw(u64 w){return __uint_as_float((unsigned)w);}

// poll one tagged word until tag==s
DEV float poll1(const u64* p,int s){
  u64 w=ald64(p);
  while(tg(w)!=s) w=ald64(p);
  return vlw(w);
}
// poll N tagged words (stride in u64 elems), return values
template<int N>
DEV void pollv(const u64* p0,int stride,int s,float* out){
  while(true){
    bool ok=true;
#pragma unroll
    for(int i=0;i<N;++i){u64 w=ald64(p0+(size_t)i*stride);ok&=(tg(w)==s);out[i]=vlw(w);}
    if(ok) return;
  }
}
// poll NB x N tagged words, accumulate row-sums (values consumed in-flight)
template<int NB,int N>
DEV void psum2(const u64* p0,int sb,int sn,int s,float* acc){
  while(true){
    bool ok=true;
#pragma unroll
    for(int b2=0;b2<NB;++b2){
      float a=0.f;
#pragma unroll
      for(int i=0;i<N;++i){u64 w=ald64(p0+(size_t)b2*sb+(size_t)i*sn);ok&=(tg(w)==s);a+=vlw(w);}
      acc[b2]=a;
    }
    if(ok) return;
  }
}

DEV float wsum(float v){
#pragma unroll
  for(int o=32;o;o>>=1) v+=__shfl_xor(v,o,64);
  return v;
}
DEV float wmax(float v){
#pragma unroll
  for(int o=32;o;o>>=1) v=fmaxf(v,__shfl_xor(v,o,64));
  return v;
}

// LayerNorm of NB register values (column tid of each row). 1 barrier.
template<int NB>
DEV void ln_reg(float (&v)[NB],const float* __restrict__ g,
                const float* __restrict__ bb,float* red){
  int tid=threadIdx.x,wid=tid>>6,lane=tid&63;
  float s[NB],s2[NB];
#pragma unroll
  for(int r=0;r<NB;++r){ s[r]=wsum(v[r]); s2[r]=wsum(v[r]*v[r]); }
  if(lane==0){
#pragma unroll
    for(int r=0;r<NB;++r){ red[r*4+wid]=s[r]; red[NB*4+r*4+wid]=s2[r]; }
  }
  __syncthreads();
  float gv=g[tid],bv=bb[tid];
#pragma unroll
  for(int r=0;r<NB;++r){
    float S=red[r*4+0]+red[r*4+1]+red[r*4+2]+red[r*4+3];
    float S2=red[NB*4+r*4+0]+red[NB*4+r*4+1]+red[NB*4+r*4+2]+red[NB*4+r*4+3];
    float m=S*(1.f/256.f);
    float rs=rsqrtf(S2*(1.f/256.f)-m*m+EPS_);
    v[r]=(v[r]-m)*rs*gv+bv;
  }
}

// ============================ S1: self-attention ============================
template<int NB,int L>
DEV void role_s1(float* LDS,int h,int bs,
    const float* __restrict__ sa_wqkv,const float* __restrict__ sa_bqkv,
    const float* __restrict__ sa_wo,
    const float* __restrict__ ln2_g,const float* __restrict__ ln2_b,
    const float* __restrict__ ln3_g,const float* __restrict__ ln3_b,
    const float* __restrict__ ffn_b2,const float* __restrict__ emb_b,
    float* kc,float* vc,
    const u64* r2T,u64* r3T,const u64* p3T,u64* p1T,const u64* xrowT){
  const int tid=threadIdx.x;
  float* W   =LDS;          // 96 x 260
  float* WO  =LDS+24960;    // 256 x 36
  float* XS  =LDS+34176;    // NB x 256
  float* QKV =LDS+35200;    // NB x 96
  float* SC  =LDS+35584;    // NB x 64
  float* PART=LDS+35840;    // NB x 64
  float* RED =LDS+36096;    // 64

  for(int idx=tid;idx<96*64;idx+=256){
    int row=idx>>6,i4=idx&63,which=row>>5,j=row&31;
    F4(&W[row*260+4*i4])=CF4(sa_wqkv+(size_t)L*196608+((size_t)(which*256+h*32+j))*256+4*i4);
  }
  for(int idx=tid;idx<256*8;idx+=256){
    int c=idx>>3,i=idx&7;
    F4(&WO[c*36+4*i])=CF4(sa_wo+(size_t)L*65536+(size_t)c*256+h*32+4*i);
  }
  __syncthreads();

  float dv=expf((float)(tid&~1)*(-9.210340371976184f/256.f));

  for(int t=0;t<64;++t){
    const int fv=2*t+L+1;
    if(L==0){
      float aarg=(float)t*dv;
      float peb=emb_b[tid]+((tid&1)?cosf(aarg):sinf(aarg));
      float xv[NB];
      pollv<NB>(xrowT+bs*256+tid,256,t,xv);
#pragma unroll
      for(int bi=0;bi<NB;++bi) XS[bi*256+tid]=xv[bi]+peb;
      __syncthreads();
    }else{
      // r2(l0, pre-LN2): published early by S3(l0)
      float r2v[NB];
      pollv<NB>(r2T+bs*256+tid,256,fv-1,r2v);   // tag 2t+1
      ln_reg<NB>(r2v,ln2_g,ln2_b,RED);
      // p3(l0) sums
      float s3[NB];
      psum2<NB,16>(p3T+bs*256+tid,256,2048,fv-1,s3);
      float r3v[NB];
      float fb=ffn_b2[tid];
#pragma unroll
      for(int bi=0;bi<NB;++bi) r3v[bi]=r2v[bi]+s3[bi]+fb;
      if(h==0){
#pragma unroll
        for(int bi=0;bi<NB;++bi) ast64(r3T+(bs+bi)*256+tid,mkw(r3v[bi],t+1));
      }
      ln_reg<NB>(r3v,ln3_g,ln3_b,RED+32);
#pragma unroll
      for(int bi=0;bi<NB;++bi) XS[bi*256+tid]=r3v[bi];
      __syncthreads();
    }
    // qkv for current token (96 rows x NB b, K-split 2)
    if(tid<192){
      int row=tid>>1,kq=tid&1;
      float a[NB];
#pragma unroll
      for(int bi=0;bi<NB;++bi) a[bi]=0.f;
#pragma unroll
      for(int i=0;i<32;++i){
        float4 w=F4(&W[row*260+kq*128+4*i]);
#pragma unroll
        for(int bi=0;bi<NB;++bi) a[bi]+=D4(w,F4(&XS[bi*256+kq*128+4*i]));
      }
#pragma unroll
      for(int bi=0;bi<NB;++bi) a[bi]+=__shfl_down(a[bi],1,64);
      if(kq==0){
        int which=row>>5,j=row&31;
        float bias=sa_bqkv[L*768+which*256+h*32+j];
#pragma unroll
        for(int bi=0;bi<NB;++bi){
          float v=a[bi]+bias;
          if(which==0) QKV[bi*96+j]=v;
          else{
            int off=(which==1)?32:64;
            QKV[bi*96+off+j]=v;
            float* cache=(which==1)?kc:vc;
            cache[(((size_t)L*64+(bs+bi)*8+h)*64+t)*32+j]=v;
          }
        }
      }
    }
    __syncthreads();
    // causal scores: wave->b
    {
      int bi=(tid>>6)&(NB-1),key=tid&63;
      float s=-3.0e38f;
      if(key<=t){
        float a=0.f;
        if(key==t){
#pragma unroll
          for(int i=0;i<8;++i) a+=D4(F4(&QKV[bi*96+4*i]),F4(&QKV[bi*96+32+4*i]));
        }else{
          const float4* kr=(const float4*)(kc+(((size_t)L*64+(bs+bi)*8+h)*64+key)*32);
#pragma unroll
          for(int i=0;i<8;++i) a+=D4(F4(&QKV[bi*96+4*i]),kr[i]);
        }
        s=a*SCALE_;
      }
      float mx=wmax(s);
      float e=(key<=t)?expf(s-mx):0.f;
      float sm=wsum(e);
      SC[bi*64+key]=e/sm;
    }
    __syncthreads();
    // PV
    {
      int bi=(tid>>6)&(NB-1),lane=tid&63,gg=lane>>5,col=lane&31;
      float acc=0.f;
      int k0=gg*32,k1=min(k0+32,t+1);
      for(int k=k0;k<k1;++k){
        float vv=(k==t)?QKV[bi*96+64+col]
                       :vc[(((size_t)L*64+(bs+bi)*8+h)*64+k)*32+col];
        acc+=SC[bi*64+k]*vv;
      }
      PART[bi*64+gg*32+col]=acc;
    }
    __syncthreads();
    if(tid<NB*32){
      int bi=tid>>5,col=tid&31;
      QKV[bi*96+col]=PART[bi*64+col]+PART[bi*64+32+col];  // o_h
    }
    __syncthreads();
    // out-proj partial -> tagged p1
    {
      float a[NB];
#pragma unroll
      for(int bi=0;bi<NB;++bi) a[bi]=0.f;
#pragma unroll
      for(int i=0;i<8;++i){
        float4 w=F4(&WO[tid*36+4*i]);
#pragma unroll
        for(int bi=0;bi<NB;++bi) a[bi]+=D4(w,F4(&QKV[bi*96+4*i]));
      }
#pragma unroll
      for(int bi=0;bi<NB;++bi) ast64(p1T+(h*8+bs+bi)*256+tid,mkw(a[bi],fv));
    }
    __syncthreads();   // protect QKV/XS reuse across loop iterations
  }
}

// ============================ S2: cross-attention ===========================
DEV void role_s2(float* LDS,int rid,
    const float* __restrict__ enc,
    const float* __restrict__ ca_wqkv,const float* __restrict__ ca_bqkv,
    const float* __restrict__ ca_wo,
    const float* __restrict__ ln1_g,const float* __restrict__ ln1_b,
    const float* __restrict__ ln3_g,const float* __restrict__ ln3_b,
    const float* __restrict__ sa_bo,const float* __restrict__ emb_b,
    const u64* p1T,u64* p2T,u64* r1T,const u64* r3T,const u64* xrowT){
  const int tid=threadIdx.x;
  const int b=rid>>4,h=(rid>>1)&7,l=rid&1;
  float* WQ  =LDS;          // 32 x 260
  float* WO  =LDS+8320;     // 256 x 36
  float* MK  =LDS+17536;    // 256 x 36
  float* MV  =LDS+26752;    // 256 x 36
  float* XS  =LDS+35968;    // 256
  float* PS  =LDS+36224;    // 256
  float* PART=LDS+36480;    // 256
  float* QC  =LDS+36736;    // 48
  float* RED =LDS+36784;    // 64

  // prologue (a): temp-load 64 K/V weight rows
  for(int idx=tid;idx<64*64;idx+=256){
    int row=idx>>6,i4=idx&63;
    int grow=(row<32)?(256+h*32+row):(512+h*32+row-32);
    F4(&LDS[row*260+4*i4])=CF4(ca_wqkv+(size_t)l*196608+(size_t)grow*256+4*i4);
  }
  __syncthreads();
  // (b): compute mem K/V slice into LDS
  for(int p=0;p<2;++p){
    int s=p*128+(tid>>1),kh=tid&1;
    float4 er[32];
#pragma unroll
    for(int i=0;i<32;++i) er[i]=CF4(enc+((size_t)(b*256+s))*256+kh*128+4*i);
    for(int out=0;out<64;++out){
      float a=0.f;
#pragma unroll
      for(int i=0;i<32;++i) a+=D4(F4(&LDS[out*260+kh*128+4*i]),er[i]);
      a+=__shfl_down(a,1,64);
      if(kh==0){
        if(out<32) MK[s*36+out]    =a+ca_bqkv[l*768+256+h*32+out];
        else       MV[s*36+out-32] =a+ca_bqkv[l*768+512+h*32+out-32];
      }
    }
  }
  __syncthreads();
  // (c): stationary weights
  for(int idx=tid;idx<32*64;idx+=256){
    int row=idx>>6,i4=idx&63;
    F4(&WQ[row*260+4*i4])=CF4(ca_wqkv+(size_t)l*196608+(size_t)(h*32+row)*256+4*i4);
  }
  for(int idx=tid;idx<256*8;idx+=256){
    int c=idx>>3,i=idx&7;
    F4(&WO[c*36+4*i])=CF4(ca_wo+(size_t)l*65536+(size_t)c*256+h*32+4*i);
  }
  __syncthreads();

  float dv=expf((float)(tid&~1)*(-9.210340371976184f/256.f));

  for(int t=0;t<64;++t){
    const int fv=2*t+l+1;
    // ---- EARLY: residual row (tagged) + LN while S1 does SA ----
    float xv;
    if(l==0){
      float aarg=(float)t*dv;
      float peb=emb_b[tid]+((tid&1)?cosf(aarg):sinf(aarg));
      xv=poll1(xrowT+b*256+tid,t)+peb;
    }else{
      float t0[1]={poll1(r3T+b*256+tid,t+1)};
      ln_reg<1>(t0,ln3_g,ln3_b,RED);        // LN3 (layer0)
      xv=t0[0];
    }
    // ---- LATE: p1 sum (tagged; detect==fetch) ----
    float s1[1];
    psum2<1,8>(p1T+b*256+tid,0,2048,fv,s1);
    float r1v=xv+s1[0]+sa_bo[l*256+tid];
    if(h==0) ast64(r1T+l*2048+b*256+tid,mkw(r1v,fv));
    float t1[1]={r1v};
    ln_reg<1>(t1,ln1_g+l*256,ln1_b+l*256,RED+8);
    XS[tid]=t1[0];
    __syncthreads();
    // qc: 8 lanes per col
    {
      int col=tid>>3,g=tid&7;
      float a=0.f;
#pragma unroll
      for(int i=0;i<8;++i) a+=D4(F4(&WQ[col*260+g*32+4*i]),F4(&XS[g*32+4*i]));
      a+=__shfl_down(a,4,64);a+=__shfl_down(a,2,64);a+=__shfl_down(a,1,64);
      if(g==0) QC[col]=a+ca_bqkv[l*768+h*32+col];
    }
    __syncthreads();
    // scores over 256 memory positions (single-merge softmax)
    {
      float a=0.f;
#pragma unroll
      for(int i=0;i<8;++i) a+=D4(F4(&MK[tid*36+4*i]),F4(&QC[4*i]));
      float sv=a*SCALE_;
      int wid=tid>>6,lane=tid&63;
      float mw=wmax(sv);
      float e=expf(sv-mw);
      float sw=wsum(e);
      if(lane==0){RED[16+wid]=mw;RED[20+wid]=sw;}
      __syncthreads();
      float M=fmaxf(fmaxf(RED[16],RED[17]),fmaxf(RED[18],RED[19]));
      float tot=RED[20]*expf(RED[16]-M)+RED[21]*expf(RED[17]-M)
               +RED[22]*expf(RED[18]-M)+RED[23]*expf(RED[19]-M);
      PS[tid]=e*expf(mw-M)/tot;
    }
    __syncthreads();
    {
      int gg=tid>>5,col=tid&31;
      float acc=0.f;
      for(int s2=gg*32;s2<gg*32+32;++s2) acc+=PS[s2]*MV[s2*36+col];
      PART[gg*32+col]=acc;
    }
    __syncthreads();
    if(tid<32){
      float o=0.f;
#pragma unroll
      for(int g2=0;g2<8;++g2) o+=PART[g2*32+tid];
      QC[tid]=o;
    }
    __syncthreads();
    {
      float a=0.f;
#pragma unroll
      for(int i=0;i<8;++i) a+=D4(F4(&WO[tid*36+4*i]),F4(&QC[4*i]));
      ast64(p2T+(h*8+b)*256+tid,mkw(a,fv));
    }
    __syncthreads();
  }
}

// ================================ S3: FFN ==================================
DEV void role_s3(float* LDS,int rid,
    const float* __restrict__ ffn_w1,const float* __restrict__ ffn_b1,
    const float* __restrict__ ffn_w2,
    const float* __restrict__ ln1_g,const float* __restrict__ ln1_b,
    const float* __restrict__ ln2_g,const float* __restrict__ ln2_b,
    const float* __restrict__ ca_bo,
    const u64* p2T,u64* p3T,const u64* r1T,u64* r2T){
  const int tid=threadIdx.x;
  const int l=rid>>5,cg=(rid>>1)&15,bh=rid&1,bs=bh*4;
  float* W1 =LDS;           // 64 x 260
  float* W2T=LDS+16640;     // 64 x 260 (transposed: [k][c])
  float* X4 =LDS+33280;     // 4 x 256
  float* HH =LDS+34304;     // 4 x 68
  float* RED=LDS+34576;     // 64

  for(int idx=tid;idx<64*64;idx+=256){
    int row=idx>>6,i4=idx&63;
    F4(&W1[row*260+4*i4])=CF4(ffn_w1+(size_t)l*262144+(size_t)(cg*64+row)*256+4*i4);
  }
  for(int idx=tid;idx<256*16;idx+=256){
    int cc=idx>>4,k4=idx&15;
    float4 w=CF4(ffn_w2+(size_t)l*262144+(size_t)cc*1024+cg*64+4*k4);
    W2T[(4*k4+0)*260+cc]=w.x;W2T[(4*k4+1)*260+cc]=w.y;
    W2T[(4*k4+2)*260+cc]=w.z;W2T[(4*k4+3)*260+cc]=w.w;
  }
  __syncthreads();

  for(int t=0;t<64;++t){
    const int fv=2*t+l+1;
    // ---- EARLY: r1 (tagged, published by S2 before its CA) + LN1 ----
    float r1v[4];
    pollv<4>(r1T+l*2048+bs*256+tid,256,fv,r1v);
    ln_reg<4>(r1v,ln1_g+l*256,ln1_b+l*256,RED);
    // ---- LATE: p2 sums ----
    float s2v[4];
    psum2<4,8>(p2T+bs*256+tid,256,2048,fv,s2v);
    float r2v[4];
    float cb=ca_bo[l*256+tid];
#pragma unroll
    for(int bi=0;bi<4;++bi) r2v[bi]=r1v[bi]+s2v[bi]+cb;
    if(cg==0){
#pragma unroll
      for(int bi=0;bi<4;++bi) ast64(r2T+l*2048+(bs+bi)*256+tid,mkw(r2v[bi],fv));
    }
    ln_reg<4>(r2v,ln2_g+l*256,ln2_b+l*256,RED+32);
#pragma unroll
    for(int bi=0;bi<4;++bi) X4[bi*256+tid]=r2v[bi];
    __syncthreads();
    // FFN1: 64 rows x 4 b, K-split 4
    {
      int row=tid>>2,kq=tid&3;
      float a0=0.f,a1=0.f,a2=0.f,a3=0.f;
#pragma unroll
      for(int i=0;i<16;++i){
        float4 w=F4(&W1[row*260+kq*64+4*i]);
        a0+=D4(w,F4(&X4[0*256+kq*64+4*i]));a1+=D4(w,F4(&X4[1*256+kq*64+4*i]));
        a2+=D4(w,F4(&X4[2*256+kq*64+4*i]));a3+=D4(w,F4(&X4[3*256+kq*64+4*i]));
      }
      a0+=__shfl_down(a0,2,64);a0+=__shfl_down(a0,1,64);
      a1+=__shfl_down(a1,2,64);a1+=__shfl_down(a1,1,64);
      a2+=__shfl_down(a2,2,64);a2+=__shfl_down(a2,1,64);
      a3+=__shfl_down(a3,2,64);a3+=__shfl_down(a3,1,64);
      if(kq==0){
        float b1v=ffn_b1[l*1024+cg*64+row];
        HH[0*68+row]=fmaxf(a0+b1v,0.f);HH[1*68+row]=fmaxf(a1+b1v,0.f);
        HH[2*68+row]=fmaxf(a2+b1v,0.f);HH[3*68+row]=fmaxf(a3+b1v,0.f);
      }
    }
    __syncthreads();
    // FFN2 partial over this 64-wide k-slice, all 256 out cols -> tagged p3
    {
      int chunk=tid&63,bi=tid>>6;
      float ax=0.f,ay=0.f,az=0.f,aw=0.f;
      for(int k=0;k<64;++k){
        float4 w=F4(&W2T[k*260+4*chunk]);
        float hv=HH[bi*68+k];
        ax+=w.x*hv;ay+=w.y*hv;az+=w.z*hv;aw+=w.w*hv;
      }
      u64* dst=p3T+(size_t)l*32768+(size_t)(cg*8+bs+bi)*256+4*chunk;
      ast64(dst+0,mkw(ax,fv));ast64(dst+1,mkw(ay,fv));
      ast64(dst+2,mkw(az,fv));ast64(dst+3,mkw(aw,fv));
    }
    __syncthreads();
  }
}

// ========================= HEAD: per-b full head ===========================
DEV void role_head(float* LDS,int b,
    const float* __restrict__ op_w1,const float* __restrict__ op_b1,
    const float* __restrict__ bn_g,const float* __restrict__ bn_b,
    const float* __restrict__ op_w2,const float* __restrict__ op_b2,
    const float* __restrict__ emb_w,
    const float* __restrict__ ln2_g,const float* __restrict__ ln2_b,
    const float* __restrict__ ln3_g,const float* __restrict__ ln3_b,
    const float* __restrict__ ffn_b2,
    const u64* p3T,const u64* r2T,u64* xrowT,float* outp){
  const int tid=threadIdx.x;
  float* X  =LDS;           // 256
  float* Y  =LDS+256;       // 256
  float* LG =LDS+512;       // 128
  float* RED=LDS+768;       // 64

  for(int t=0;t<64;++t){
    const int fv=2*t+2;
    // ---- EARLY: r2(l1) + LN2 while S3(l1) does its FFN ----
    float t0[1]={poll1(r2T+2048+b*256+tid,fv)};
    ln_reg<1>(t0,ln2_g+256,ln2_b+256,RED);
    // ---- LATE: p3(l1) sum ----
    float s3[1];
    psum2<1,16>(p3T+32768+b*256+tid,0,2048,fv,s3);
    float r3=t0[0]+s3[0]+ffn_b2[256+tid];
    float t1[1]={r3};
    ln_reg<1>(t1,ln3_g+256,ln3_b+256,RED+8);
    X[tid]=t1[0];
    __syncthreads();
    // y = X @ op_w1.T + b1, bn affine + relu.  K-split 16.
    {
      int g=tid&15,cc=tid>>4;
      for(int it=0;it<16;++it){
        int c2=it*16+cc;
        const float4* w4=(const float4*)(op_w1+(size_t)c2*256+g*16);
        const float4* x4=(const float4*)(X+g*16);
        float a=0.f;
#pragma unroll
        for(int i=0;i<4;++i) a+=D4(w4[i],x4[i]);
        a+=__shfl_down(a,8,64);a+=__shfl_down(a,4,64);
        a+=__shfl_down(a,2,64);a+=__shfl_down(a,1,64);
        if(g==0){
          float y=a+op_b1[c2];
          Y[c2]=fmaxf(y*BNS*bn_g[c2]+bn_b[c2],0.f);
        }
      }
    }
    __syncthreads();
    // logits = Y @ op_w2.T + b2 (128 cols), write out. K-split 16.
    {
      int g=tid&15,cc=tid>>4;
      for(int it=0;it<8;++it){
        int c2=it*16+cc;
        const float4* w4=(const float4*)(op_w2+(size_t)c2*256+g*16);
        const float4* y4=(const float4*)(Y+g*16);
        float a=0.f;
#pragma unroll
        for(int i=0;i<4;++i) a+=D4(w4[i],y4[i]);
        a+=__shfl_down(a,8,64);a+=__shfl_down(a,4,64);
        a+=__shfl_down(a,2,64);a+=__shfl_down(a,1,64);
        if(g==0){
          float v=a+op_b2[c2];
          LG[c2]=v;
          outp[((size_t)b*64+t)*128+c2]=v;
        }
      }
    }
    __syncthreads();
    // xrow[b][c] = LG . emb_w[c,:]  (K=128, K-split 8) -> tagged t+1
    if(t<63){
      int g=tid&7,cc=tid>>3;
      for(int it=0;it<8;++it){
        int c2=it*32+cc;
        const float4* w4=(const float4*)(emb_w+(size_t)c2*128+g*16);
        const float4* l4=(const float4*)(LG+g*16);
        float a=0.f;
#pragma unroll
        for(int i=0;i<4;++i) a+=D4(w4[i],l4[i]);
        a+=__shfl_down(a,4,64);a+=__shfl_down(a,2,64);a+=__shfl_down(a,1,64);
        if(g==0) ast64(xrowT+b*256+c2,mkw(a,t+1));
      }
    }
    __syncthreads();
  }
}

// ---------------------------------------------------------------------------

__global__ void __launch_bounds__(256,1) k_decode(
    const float* enc,const float* emb_w,const float* emb_b,
    const float* sa_wqkv,const float* sa_bqkv,const float* sa_wo,const float* sa_bo,
    const float* ca_wqkv,const float* ca_bqkv,const float* ca_wo,const float* ca_bo,
    const float* ln1_g,const float* ln1_b,const float* ln2_g,const float* ln2_b,
    const float* ffn_w1,const float* ffn_b1,const float* ffn_w2,const float* ffn_b2,
    const float* ln3_g,const float* ln3_b,
    const float* op_w1,const float* op_b1,const float* bn_g,const float* bn_b,
    const float* op_w2,const float* op_b2,
    u64* xrowT,u64* r3T,u64* r1T,u64* r2T,u64* p1T,u64* p2T,u64* p3T,
    float* kc,float* vc,float* outp){
  __shared__ __align__(16) float LDS[DYNF];
  const int blk=blockIdx.x;
  if(blk<16){
    role_s1<4,0>(LDS,blk>>1,(blk&1)*4,sa_wqkv,sa_bqkv,sa_wo,ln2_g,ln2_b,ln3_g,ln3_b,
                 ffn_b2,emb_b,kc,vc,r2T,r3T,p3T,p1T,xrowT);
  }else if(blk<48){
    int r=blk-16;
    role_s1<2,1>(LDS,r>>2,(r&3)*2,sa_wqkv,sa_bqkv,sa_wo,ln2_g,ln2_b,ln3_g,ln3_b,
                 ffn_b2,emb_b,kc,vc,r2T,r3T,p3T,p1T,xrowT);
  }else if(blk<176){
    role_s2(LDS,blk-48,enc,ca_wqkv,ca_bqkv,ca_wo,ln1_g,ln1_b,ln3_g,ln3_b,sa_bo,emb_b,
            p1T,p2T,r1T,r3T,xrowT);
  }else if(blk<240){
    role_s3(LDS,blk-176,ffn_w1,ffn_b1,ffn_w2,ln1_g,ln1_b,ln2_g,ln2_b,ca_bo,
            p2T,p3T,r1T,r2T);
  }else{
    role_head(LDS,blk-240,op_w1,op_b1,bn_g,bn_b,op_w2,op_b2,emb_w,
              ln2_g,ln2_b,ln3_g,ln3_b,ffn_b2,p3T,r2T,xrowT,outp);
  }
}

// ---------------------------------------------------------------------------

extern "C" void kernel_launch(void* const* d_in, const int* in_sizes, int n_in,
                              void* d_out, int out_size, void* d_ws, size_t ws_size,
                              hipStream_t stream) {
  (void)in_sizes;(void)n_in;(void)out_size;(void)ws_size;
  const float* enc     =(const float*)d_in[0];
  const float* emb_w   =(const float*)d_in[1];
  const float* emb_b   =(const float*)d_in[2];
  const float* sa_wqkv =(const float*)d_in[3];
  const float* sa_bqkv =(const float*)d_in[4];
  const float* sa_wo   =(const float*)d_in[5];
  const float* sa_bo   =(const float*)d_in[6];
  const float* ca_wqkv =(const float*)d_in[7];
  const float* ca_bqkv =(const float*)d_in[8];
  const float* ca_wo   =(const float*)d_in[9];
  const float* ca_bo   =(const float*)d_in[10];
  const float* ln1_g   =(const float*)d_in[11];
  const float* ln1_b   =(const float*)d_in[12];
  const float* ln2_g   =(const float*)d_in[13];
  const float* ln2_b   =(const float*)d_in[14];
  const float* ffn_w1  =(const float*)d_in[15];
  const float* ffn_b1  =(const float*)d_in[16];
  const float* ffn_w2  =(const float*)d_in[17];
  const float* ffn_b2  =(const float*)d_in[18];
  const float* ln3_g   =(const float*)d_in[19];
  const float* ln3_b   =(const float*)d_in[20];
  const float* op_w1   =(const float*)d_in[21];
  const float* op_b1   =(const float*)d_in[22];
  const float* bn_g    =(const float*)d_in[23];
  const float* bn_b    =(const float*)d_in[24];
  const float* op_w2   =(const float*)d_in[25];
  const float* op_b2   =(const float*)d_in[26];

  float* out=(float*)d_out;

  // Tagged transport region (u64 each = float payload | seq tag).
  u64* T=(u64*)d_ws;
  u64* xrowT=T;              // 8 x 256                     [0,2048)
  u64* r3T  =T+2048;         // 8 x 256                     [2048,4096)
  u64* r1T  =T+4096;         // 2l x 8b x 256               [4096,8192)
  u64* r2T  =T+8192;         // 2l x 8b x 256               [8192,12288)
  u64* p1T  =T+12288;        // 8h x 8b x 256               [12288,28672)
  u64* p2T  =T+28672;        // 8h x 8b x 256               [28672,45056)
  u64* p3T  =T+45056;        // 2l x 16cg x 8b x 256        [45056,110592)
  // zero ALL tags each call (ABA-safe across graph replays; tag0=valid t=0)
  hipMemsetAsync(d_ws,0,110592*sizeof(u64),stream);

  float* kc=(float*)(T+110592);  // 2 x 8 x 8 x 64 x 32
  float* vc=kc+262144;

  k_decode<<<248,256,0,stream>>>(
      enc,emb_w,emb_b,sa_wqkv,sa_bqkv,sa_wo,sa_bo,
      ca_wqkv,ca_bqkv,ca_wo,ca_bo,ln1_g,ln1_b,ln2_g,ln2_b,
      ffn_w1,ffn_b1,ffn_w2,ffn_b2,ln3_g,ln3_b,
      op_w1,op_b1,bn_g,bn_b,op_w2,op_b2,
      xrowT,r3T,r1T,r2T,p1T,p2T,p3T,kc,vc,out);
}